// Round 8
// baseline (130.536 us; speedup 1.0000x reference)
//
#include <hip/hip_runtime.h>
#include <hip/hip_bf16.h>
#include <stdint.h>

#define NVAR 32
#define LAGD 1024
#define BATCH 256
#define HDIM 512
#define SPLIT 16

typedef __attribute__((ext_vector_type(4))) float f32x4;
typedef __attribute__((ext_vector_type(8))) short short8;
typedef __attribute__((ext_vector_type(4))) unsigned short us4;
typedef __attribute__((ext_vector_type(8))) unsigned short us8;

__device__ __forceinline__ unsigned short f2bf(float f) {
  union { __hip_bfloat16 b; unsigned short s; } cv;
  cv.b = __float2bfloat16(f);
  return cv.s;
}
__device__ __forceinline__ us8 cvt8(f32x4 a, f32x4 b) {
  us8 u;
#pragma unroll
  for (int e = 0; e < 4; ++e) { u[e] = f2bf(a[e]); u[4 + e] = f2bf(b[e]); }
  return u;
}
__device__ __forceinline__ us4 cvt4(f32x4 a) {
  us4 u;
#pragma unroll
  for (int e = 0; e < 4; ++e) u[e] = f2bf(a[e]);
  return u;
}

// global -> LDS direct copy, 16 B per lane (dest = wave-uniform base + lane*16).
__device__ __forceinline__ void gload16(const void* g, const void* l) {
  __builtin_amdgcn_global_load_lds(
      (const __attribute__((address_space(1))) unsigned int*)(uintptr_t)g,
      (__attribute__((address_space(3))) unsigned int*)(unsigned int)(uintptr_t)l,
      16, 0, 0);
}

// Order-pinned global load (asm volatile keeps FIFO position).
__device__ __forceinline__ f32x4 gldx4(const float* p) {
  f32x4 r;
  asm volatile("global_load_dwordx4 %0, %1, off" : "=v"(r) : "v"(p) : "memory");
  return r;
}

// Counted vmem wait; sched_barrier stops hipcc hoisting dependent ops above it.
#define WAITVM(N) do { \
    asm volatile("s_waitcnt vmcnt(" #N ")" ::: "memory"); \
    __builtin_amdgcn_sched_barrier(0); } while (0)

// Barrier that does NOT drain vmcnt (prefetch survives across it).
__device__ __forceinline__ void sync_ds() {
  asm volatile("s_waitcnt lgkmcnt(0)" ::: "memory");
  __builtin_amdgcn_s_barrier();
}

// ---------------------------------------------------------------------------
// K1: gates GEMM + LSTM activation (round-6 structure: 2 blocks/CU,
//   counted-vmcnt FIFO, reg-staged fp32 X, depth-2 W prefetch).
// ---------------------------------------------------------------------------
__global__ __launch_bounds__(512, 4) void k1_gates(
    const float* __restrict__ X,          // [256][32][1024]
    const float* __restrict__ W,          // [32][2048][1024]
    const float* __restrict__ b_ih,
    const float* __restrict__ b_hh,
    const float* __restrict__ imp,
    unsigned short* __restrict__ aggT)    // [32 v][8 kt][256][64] swizzled bf16
{
  const int bid = blockIdx.x;
  const int chunk = ((bid & 7) << 6) | (bid >> 3);   // XCD-contiguous
  const int v = chunk >> 4;
  const int h0 = (chunk & 15) << 5;

  const int t = threadIdx.x, lane = t & 63, wave = t >> 6;
  const int wm = wave & 3, wh = wave >> 2;

  __shared__ __align__(16) unsigned char smem[81920]; // A:2x32K @0, B:2x8K @65536

  const int rt = t >> 3, c8 = (t & 7) << 3;
  const float* Asrc = X + (size_t)rt * (NVAR * LAGD) + (size_t)v * LAGD + c8;
  const unsigned awoff = (unsigned)(((rt << 7) + (c8 << 1)) ^ ((rt & 7) << 4));

  const int brow = t >> 3;
  const int wrow = (brow < 32) ? (h0 + brow) : (1024 + h0 + brow - 32);
  const float* Bsrc = W + (size_t)v * (2048 * LAGD) + (size_t)wrow * LAGD + ((t & 7) << 3);
  const unsigned bwoff = (unsigned)(((brow << 7) + ((t & 7) << 4)) ^ ((brow & 7) << 4));

  f32x4 acc_i[4] = {}, acc_g[4] = {};
  f32x4 pa[4][2], pbA[2], pbB[2];

#define ALOAD(KT) do { \
    _Pragma("unroll") for (int _p = 0; _p < 4; ++_p) { \
      pa[_p][0] = gldx4(Asrc + (size_t)_p * 64 * (NVAR * LAGD) + (KT) * 64); \
      pa[_p][1] = gldx4(Asrc + (size_t)_p * 64 * (NVAR * LAGD) + (KT) * 64 + 4); \
    } } while (0)

#define ASTORE(BUF) do { \
    _Pragma("unroll") for (int _p = 0; _p < 4; ++_p) \
      *(us8*)(smem + (BUF) * 32768u + awoff + _p * 8192u) = cvt8(pa[_p][0], pa[_p][1]); \
  } while (0)

#define BLOAD(PB, KT) do { \
    (PB)[0] = gldx4(Bsrc + (KT) * 64); \
    (PB)[1] = gldx4(Bsrc + (KT) * 64 + 4); } while (0)

#define BSTORE(BUF, PB) \
    *(us8*)(smem + 65536u + (BUF) * 8192u + bwoff) = cvt8((PB)[0], (PB)[1])

#define COMP(BUF) do { \
    const unsigned char* Ab = smem + (BUF) * 32768u; \
    const unsigned char* Bb = smem + 65536u + (BUF) * 8192u; \
    const int fr = lane & 15, k16 = (lane >> 4) << 4; \
    _Pragma("unroll") for (int kk = 0; kk < 2; ++kk) { \
      short8 a[4], fi, fg; \
      _Pragma("unroll") for (int i = 0; i < 4; ++i) { \
        const int rw = (wm << 6) + (i << 4) + fr; \
        a[i] = *(const short8*)(Ab + (((rw << 7) + (kk << 6) + k16) ^ ((rw & 7) << 4))); \
      } \
      { const int rw = (wh << 4) + fr; \
        fi = *(const short8*)(Bb + (((rw << 7) + (kk << 6) + k16) ^ ((rw & 7) << 4))); \
        fg = *(const short8*)(Bb + ((((rw + 32) << 7) + (kk << 6) + k16) ^ ((rw & 7) << 4))); } \
      _Pragma("unroll") for (int i = 0; i < 4; ++i) { \
        acc_i[i] = __builtin_amdgcn_mfma_f32_16x16x32_bf16(a[i], fi, acc_i[i], 0, 0, 0); \
        acc_g[i] = __builtin_amdgcn_mfma_f32_16x16x32_bf16(a[i], fg, acc_g[i], 0, 0, 0); } \
    } } while (0)

#define STEP(CUR, NXT, PBP, PBN, KT) do { \
    ALOAD((KT) + 1); \
    BLOAD(PBN, (KT) + 2); \
    COMP(CUR); \
    WAITVM(2); \
    ASTORE(NXT); \
    BSTORE(NXT, PBP); \
    sync_ds(); } while (0)

  ALOAD(0);
  BLOAD(pbA, 0);
  BLOAD(pbB, 1);
  WAITVM(2);
  ASTORE(0);
  BSTORE(0, pbA);
  sync_ds();

#pragma unroll
  for (int kt = 0; kt < 14; kt += 2) {
    STEP(0, 1, pbB, pbA, kt);
    STEP(1, 0, pbA, pbB, kt + 1);
  }
  ALOAD(15);
  COMP(0);
  WAITVM(0);
  ASTORE(1);
  BSTORE(1, pbB);
  sync_ds();
  COMP(1);

  const int col16 = lane & 15, row4 = (lane >> 4) << 2;
  const float impv = imp[v];
  const int h = h0 + (wh << 4) + col16;
  const float bsi = b_ih[v * 2048 + h] + b_hh[v * 2048 + h];
  const float bsg = b_ih[v * 2048 + 1024 + h] + b_hh[v * 2048 + 1024 + h];
  char* obase = (char*)aggT + ((size_t)v * 8 + (h >> 6)) * 32768;
  const int hc = h & 63;
#pragma unroll
  for (int i = 0; i < 4; ++i)
#pragma unroll
    for (int r = 0; r < 4; ++r) {
      const int m = (wm << 6) + (i << 4) + row4 + r;
      const float ii = acc_i[i][r] + bsi;
      const float gg = acc_g[i][r] + bsg;
      const float c = (1.0f / (1.0f + __expf(-ii))) * tanhf(gg) * impv;
      *(unsigned short*)(obase + (((m << 7) + (hc << 1)) ^ ((m & 7) << 4))) = f2bf(c);
    }
#undef STEP
#undef COMP
#undef ALOAD
#undef ASTORE
#undef BLOAD
#undef BSTORE
}

// ---------------------------------------------------------------------------
// K3: mlp1 split-K GEMM (round-6 structure).
// ---------------------------------------------------------------------------
__global__ __launch_bounds__(512, 4) void k3_mlp1(
    const unsigned short* __restrict__ aggT,
    const float* __restrict__ Wm,          // [1024][16384]
    unsigned short* __restrict__ part)     // [16][256][1024] bf16
{
  const int bid = blockIdx.x;
  const int chunk = ((bid & 7) << 6) | (bid >> 3);
  const int s = chunk >> 5;                 // 0..15
  const int n0 = (chunk & 31) << 5;         // 0..992

  const int t = threadIdx.x, lane = t & 63, wave = t >> 6;
  const int wm = wave & 3, wn = wave >> 2;

  __shared__ __align__(16) unsigned char smem[73728];

  const char* Asrc = (const char*)aggT + (size_t)s * 16 * 32768 + wave * 1024 + lane * 16;
  const unsigned aoff = wave * 1024u;

  const int brow = t >> 4;
  const int bcol = (t & 15) << 2;
  const float* Bsrc = Wm + (size_t)(n0 + brow) * 16384 + (size_t)s * 1024 + bcol;
  const unsigned bwoff = (unsigned)(((brow << 7) + (bcol << 1)) ^ ((brow & 7) << 4));

  f32x4 acc[4] = {};
  f32x4 pbA, pbB;

#define GLA(BUF, KT) do { \
    _Pragma("unroll") for (int _r = 0; _r < 4; ++_r) \
      gload16(Asrc + (KT) * 32768 + _r * 8192, \
              smem + (BUF) * 32768u + aoff + _r * 8192); } while (0)

#define BLOAD(PB, KT) (PB) = gldx4(Bsrc + (KT) * 64)

#define BSTORE(BUF, PB) \
    *(us4*)(smem + 65536u + (BUF) * 4096u + bwoff) = cvt4(PB)

#define COMP(BUF) do { \
    const unsigned char* Ab = smem + (BUF) * 32768u; \
    const unsigned char* Bb = smem + 65536u + (BUF) * 4096u; \
    const int fr = lane & 15, k16 = (lane >> 4) << 4; \
    _Pragma("unroll") for (int kk = 0; kk < 2; ++kk) { \
      short8 a[4], bfr; \
      _Pragma("unroll") for (int i = 0; i < 4; ++i) { \
        const int rw = (wm << 6) + (i << 4) + fr; \
        a[i] = *(const short8*)(Ab + (((rw << 7) + (kk << 6) + k16) ^ ((rw & 7) << 4))); \
      } \
      { const int rw = (wn << 4) + fr; \
        bfr = *(const short8*)(Bb + (((rw << 7) + (kk << 6) + k16) ^ ((rw & 7) << 4))); } \
      _Pragma("unroll") for (int i = 0; i < 4; ++i) \
        acc[i] = __builtin_amdgcn_mfma_f32_16x16x32_bf16(a[i], bfr, acc[i], 0, 0, 0); \
    } } while (0)

#define STEP(CUR, NXT, PBP, PBN, KT) do { \
    GLA(NXT, (KT) + 1); \
    BLOAD(PBN, (KT) + 2); \
    COMP(CUR); \
    WAITVM(1); \
    BSTORE(NXT, PBP); \
    sync_ds(); } while (0)

  GLA(0, 0);
  BLOAD(pbA, 0);
  BLOAD(pbB, 1);
  WAITVM(1);
  BSTORE(0, pbA);
  sync_ds();

#pragma unroll
  for (int kt = 0; kt < 14; kt += 2) {
    STEP(0, 1, pbB, pbA, kt);
    STEP(1, 0, pbA, pbB, kt + 1);
  }
  GLA(1, 15);
  COMP(0);
  WAITVM(0);
  BSTORE(1, pbB);
  sync_ds();
  COMP(1);

  const int col16 = lane & 15, row4 = (lane >> 4) << 2;
  unsigned short* outp = part + (size_t)s * BATCH * 1024;
#pragma unroll
  for (int i = 0; i < 4; ++i)
#pragma unroll
    for (int r = 0; r < 4; ++r)
      outp[(size_t)((wm << 6) + (i << 4) + row4 + r) * 1024
           + n0 + (wn << 4) + col16] = f2bf(acc[i][r]);
#undef STEP
#undef COMP
#undef GLA
#undef BLOAD
#undef BSTORE
}

// ---------------------------------------------------------------------------
// K4: fused head (bf16 partials). One block per batch row, 512 threads.
// ---------------------------------------------------------------------------
__global__ __launch_bounds__(512) void k4_head(
    const unsigned short* __restrict__ part,   // [16][256][1024] bf16
    const float* __restrict__ b1,
    const float* __restrict__ w2,
    const float* __restrict__ b2,
    float* __restrict__ out)
{
  const int b = blockIdx.x;
  const int t = threadIdx.x;
  const int n0 = t << 1;
  float s0 = b1[n0], s1 = b1[n0 + 1];
#pragma unroll
  for (int sp = 0; sp < SPLIT; ++sp) {
    const unsigned u = *(const unsigned*)(part + ((size_t)sp * BATCH + b) * 1024 + n0);
    union { unsigned u; float f; } lo, hi;
    lo.u = u << 16;
    hi.u = u & 0xffff0000u;
    s0 += lo.f;
    s1 += hi.f;
  }
  float accum = fmaxf(s0, 0.0f) * w2[n0] + fmaxf(s1, 0.0f) * w2[n0 + 1];
  __shared__ float red[8];
#pragma unroll
  for (int off = 32; off > 0; off >>= 1)
    accum += __shfl_down(accum, off);
  if ((t & 63) == 0) red[t >> 6] = accum;
  __syncthreads();
  if (t == 0) {
    float r = b2[0];
#pragma unroll
    for (int w = 0; w < 8; ++w) r += red[w];
    out[b] = r;
  }
}

// ---------------------------------------------------------------------------
// MEASUREMENT ROUND: k1 and k3 are idempotent (pure functions of inputs /
// upstream intermediates), so launching each twice is deterministic and lets
// us read T(k1)+T(k3) off the total-time delta vs round 6's 69.1 us.
// ---------------------------------------------------------------------------
extern "C" void kernel_launch(void* const* d_in, const int* in_sizes, int n_in,
                              void* d_out, int out_size, void* d_ws, size_t ws_size,
                              hipStream_t stream) {
  const float* inputs = (const float*)d_in[0];
  const float* W_ih   = (const float*)d_in[1];
  // d_in[2] = W_hh: unused (h0 == 0)
  const float* b_ih   = (const float*)d_in[3];
  const float* b_hh   = (const float*)d_in[4];
  const float* imp    = (const float*)d_in[5];
  const float* m1w    = (const float*)d_in[6];
  const float* m1b    = (const float*)d_in[7];
  const float* m2w    = (const float*)d_in[8];
  const float* m2b    = (const float*)d_in[9];
  float* out = (float*)d_out;

  char* ws = (char*)d_ws;
  unsigned short* aggT = (unsigned short*)ws;                // 8 MB tiled bf16
  unsigned short* part = (unsigned short*)(ws + (8u << 20)); // 8 MB bf16

  k1_gates<<<dim3(512), 512, 0, stream>>>(inputs, W_ih, b_ih, b_hh, imp, aggT);
  k1_gates<<<dim3(512), 512, 0, stream>>>(inputs, W_ih, b_ih, b_hh, imp, aggT);
  k3_mlp1 <<<dim3(512), 512, 0, stream>>>(aggT, m1w, part);
  k3_mlp1 <<<dim3(512), 512, 0, stream>>>(aggT, m1w, part);
  k4_head <<<dim3(256), 512, 0, stream>>>(part, m1b, m2w, m2b, out);
}

// Round 9
// 85.006 us; speedup vs baseline: 1.5356x; 1.5356x over previous
//
#include <hip/hip_runtime.h>
#include <hip/hip_bf16.h>
#include <stdint.h>

#define NVAR 32
#define LAGD 1024
#define BATCH 256
#define HDIM 512
#define SPLIT 16

typedef __attribute__((ext_vector_type(4))) float f32x4;
typedef __attribute__((ext_vector_type(8))) short short8;
typedef __attribute__((ext_vector_type(4))) unsigned short us4;
typedef __attribute__((ext_vector_type(8))) unsigned short us8;

__device__ __forceinline__ unsigned short f2bf(float f) {
  union { __hip_bfloat16 b; unsigned short s; } cv;
  cv.b = __float2bfloat16(f);
  return cv.s;
}
__device__ __forceinline__ us8 cvt8(f32x4 a, f32x4 b) {
  us8 u;
#pragma unroll
  for (int e = 0; e < 4; ++e) { u[e] = f2bf(a[e]); u[4 + e] = f2bf(b[e]); }
  return u;
}
__device__ __forceinline__ us4 cvt4(f32x4 a) {
  us4 u;
#pragma unroll
  for (int e = 0; e < 4; ++e) u[e] = f2bf(a[e]);
  return u;
}

// global -> LDS direct copy, 16 B per lane (dest = wave-uniform base + lane*16).
__device__ __forceinline__ void gload16(const void* g, const void* l) {
  __builtin_amdgcn_global_load_lds(
      (const __attribute__((address_space(1))) unsigned int*)(uintptr_t)g,
      (__attribute__((address_space(3))) unsigned int*)(unsigned int)(uintptr_t)l,
      16, 0, 0);
}

// Order-pinned global load (asm volatile keeps FIFO position).
__device__ __forceinline__ f32x4 gldx4(const float* p) {
  f32x4 r;
  asm volatile("global_load_dwordx4 %0, %1, off" : "=v"(r) : "v"(p) : "memory");
  return r;
}

#define WAITVM(N) do { \
    asm volatile("s_waitcnt vmcnt(" #N ")" ::: "memory"); \
    __builtin_amdgcn_sched_barrier(0); } while (0)

__device__ __forceinline__ void sync_ds() {
  asm volatile("s_waitcnt lgkmcnt(0)" ::: "memory");
  __builtin_amdgcn_s_barrier();
}

// ---------------------------------------------------------------------------
// K1: gates GEMM + LSTM activation. BM=128 (m-half per block), 48 KB LDS,
//   3 blocks/CU (24 waves). Round-6 counted-vmcnt pipeline otherwise.
//   Grid 1024 = v(32) x h0(16) x mh(2); chunk swizzle keeps a v on one XCD.
// ---------------------------------------------------------------------------
__global__ __launch_bounds__(512, 6) void k1_gates(
    const float* __restrict__ X,          // [256][32][1024]
    const float* __restrict__ W,          // [32][2048][1024]
    const float* __restrict__ b_ih,
    const float* __restrict__ b_hh,
    const float* __restrict__ imp,
    unsigned short* __restrict__ aggT)    // [32 v][8 kt][256][64] swizzled bf16
{
  const int bid = blockIdx.x;
  const int chunk = ((bid & 7) << 7) | (bid >> 3);   // XCD-contiguous, 128/XCD
  const int v  = chunk >> 5;
  const int h0 = ((chunk & 31) >> 1) << 5;           // 0..480 step 32
  const int mh = chunk & 1;

  const int t = threadIdx.x, lane = t & 63, wave = t >> 6;
  const int wm = wave & 3, wh = wave >> 2;           // 32 m-rows x 16 h-cols

  __shared__ __align__(16) unsigned char smem[49152]; // A:2x16K @0, B:2x8K @32768

  // A staging: 128 rows x 64 k fp32; thread owns row rt, 16 fp32 at c16
  const int rt = t >> 2, c16 = (t & 3) << 4;
  const float* Asrc = X + (size_t)(mh * 128 + rt) * (NVAR * LAGD) + (size_t)v * LAGD + c16;
  const unsigned aw0 = (unsigned)(((rt << 7) + (c16 << 1)) ^ ((rt & 7) << 4));
  const unsigned aw1 = (unsigned)(((rt << 7) + (c16 << 1) + 16) ^ ((rt & 7) << 4));

  // B staging: 64 rows (32 i + 32 g) x 64 k fp32; thread owns row brow, 8 fp32
  const int brow = t >> 3;
  const int wrow = (brow < 32) ? (h0 + brow) : (1024 + h0 + brow - 32);
  const float* Bsrc = W + (size_t)v * (2048 * LAGD) + (size_t)wrow * LAGD + ((t & 7) << 3);
  const unsigned bwoff = (unsigned)(((brow << 7) + ((t & 7) << 4)) ^ ((brow & 7) << 4));

  f32x4 acc_i[2] = {}, acc_g[2] = {};
  f32x4 pa[4], pbA[2], pbB[2];

#define ALOAD(KT) do { \
    _Pragma("unroll") for (int _e = 0; _e < 4; ++_e) \
      pa[_e] = gldx4(Asrc + (KT) * 64 + _e * 4); } while (0)

#define ASTORE(BUF) do { \
    *(us8*)(smem + (BUF) * 16384u + aw0) = cvt8(pa[0], pa[1]); \
    *(us8*)(smem + (BUF) * 16384u + aw1) = cvt8(pa[2], pa[3]); } while (0)

#define BLOAD(PB, KT) do { \
    (PB)[0] = gldx4(Bsrc + (KT) * 64); \
    (PB)[1] = gldx4(Bsrc + (KT) * 64 + 4); } while (0)

#define BSTORE(BUF, PB) \
    *(us8*)(smem + 32768u + (BUF) * 8192u + bwoff) = cvt8((PB)[0], (PB)[1])

#define COMP(BUF) do { \
    const unsigned char* Ab = smem + (BUF) * 16384u; \
    const unsigned char* Bb = smem + 32768u + (BUF) * 8192u; \
    const int fr = lane & 15, k16 = (lane >> 4) << 4; \
    _Pragma("unroll") for (int kk = 0; kk < 2; ++kk) { \
      short8 a[2], fi, fg; \
      _Pragma("unroll") for (int i = 0; i < 2; ++i) { \
        const int rw = (wm << 5) + (i << 4) + fr; \
        a[i] = *(const short8*)(Ab + (((rw << 7) + (kk << 6) + k16) ^ ((rw & 7) << 4))); \
      } \
      { const int rw = (wh << 4) + fr; \
        fi = *(const short8*)(Bb + (((rw << 7) + (kk << 6) + k16) ^ ((rw & 7) << 4))); \
        fg = *(const short8*)(Bb + ((((rw + 32) << 7) + (kk << 6) + k16) ^ ((rw & 7) << 4))); } \
      _Pragma("unroll") for (int i = 0; i < 2; ++i) { \
        acc_i[i] = __builtin_amdgcn_mfma_f32_16x16x32_bf16(a[i], fi, acc_i[i], 0, 0, 0); \
        acc_g[i] = __builtin_amdgcn_mfma_f32_16x16x32_bf16(a[i], fg, acc_g[i], 0, 0, 0); } \
    } } while (0)

  // STEP invariant at entry: in-flight = B(KT+1) (2 loads).
#define STEP(CUR, NXT, PBP, PBN, KT) do { \
    ALOAD((KT) + 1);        /* 4 loads */ \
    BLOAD(PBN, (KT) + 2);   /* 2 loads */ \
    COMP(CUR); \
    WAITVM(2);   /* drain A(KT+1)+B(KT+1); keep B(KT+2) */ \
    ASTORE(NXT); \
    BSTORE(NXT, PBP); \
    sync_ds(); } while (0)

  ALOAD(0);
  BLOAD(pbA, 0);
  BLOAD(pbB, 1);
  WAITVM(2);          // drain A(0)+pbA; pbB stays
  ASTORE(0);
  BSTORE(0, pbA);
  sync_ds();

#pragma unroll
  for (int kt = 0; kt < 14; kt += 2) {
    STEP(0, 1, pbB, pbA, kt);
    STEP(1, 0, pbA, pbB, kt + 1);
  }
  ALOAD(15);
  COMP(0);            // tile 14
  WAITVM(0);
  ASTORE(1);
  BSTORE(1, pbB);
  sync_ds();
  COMP(1);            // tile 15

  // epilogue: c = sigmoid(i+bi)*tanh(g+bg)*imp -> aggT (swizzled tile layout)
  const int col16 = lane & 15, row4 = (lane >> 4) << 2;
  const float impv = imp[v];
  const int h = h0 + (wh << 4) + col16;
  const float bsi = b_ih[v * 2048 + h] + b_hh[v * 2048 + h];
  const float bsg = b_ih[v * 2048 + 1024 + h] + b_hh[v * 2048 + 1024 + h];
  char* obase = (char*)aggT + ((size_t)v * 8 + (h >> 6)) * 32768;
  const int hc = h & 63;
#pragma unroll
  for (int i = 0; i < 2; ++i)
#pragma unroll
    for (int r = 0; r < 4; ++r) {
      const int m = (mh << 7) + (wm << 5) + (i << 4) + row4 + r;
      const float ii = acc_i[i][r] + bsi;
      const float gg = acc_g[i][r] + bsg;
      const float c = (1.0f / (1.0f + __expf(-ii))) * tanhf(gg) * impv;
      *(unsigned short*)(obase + (((m << 7) + (hc << 1)) ^ ((m & 7) << 4))) = f2bf(c);
    }
#undef STEP
#undef COMP
#undef ALOAD
#undef ASTORE
#undef BLOAD
#undef BSTORE
}

// ---------------------------------------------------------------------------
// K3: mlp1 split-K GEMM. BM=128, BN=32, 40 KB LDS, 4 blocks/CU (32 waves).
//   Grid 1024 = s(16) x n0(32) x mh(2).
// ---------------------------------------------------------------------------
__global__ __launch_bounds__(512, 8) void k3_mlp1(
    const unsigned short* __restrict__ aggT,
    const float* __restrict__ Wm,          // [1024][16384]
    unsigned short* __restrict__ part)     // [16][256][1024] bf16
{
  const int bid = blockIdx.x;
  const int chunk = ((bid & 7) << 7) | (bid >> 3);
  const int s  = chunk >> 6;                 // 0..15
  const int n0 = ((chunk & 63) >> 1) << 5;   // 0..992 step 32
  const int mh = chunk & 1;

  const int t = threadIdx.x, lane = t & 63, wave = t >> 6;
  const int wm = wave & 3, wn = wave >> 2;   // 32 m-rows x 16 n-cols

  __shared__ __align__(16) unsigned char smem[40960]; // A:2x16K @0, B:2x4K @32768

  const char* Asrc = (const char*)aggT + (size_t)s * 16 * 32768 + mh * 16384
                     + wave * 2048 + lane * 16;

  const int brow = t >> 4;                   // 0..31
  const int bcol = (t & 15) << 2;            // 0..60
  const float* Bsrc = Wm + (size_t)(n0 + brow) * 16384 + (size_t)s * 1024 + bcol;
  const unsigned bwoff = (unsigned)(((brow << 7) + (bcol << 1)) ^ ((brow & 7) << 4));

  f32x4 acc[2] = {};
  f32x4 pbA, pbB;

#define GLA(BUF, KT) do { \
    _Pragma("unroll") for (int _r = 0; _r < 2; ++_r) \
      gload16(Asrc + (KT) * 32768 + _r * 1024, \
              smem + (BUF) * 16384u + wave * 2048u + _r * 1024u); } while (0)

#define BLOAD(PB, KT) (PB) = gldx4(Bsrc + (KT) * 64)

#define BSTORE(BUF, PB) \
    *(us4*)(smem + 32768u + (BUF) * 4096u + bwoff) = cvt4(PB)

#define COMP(BUF) do { \
    const unsigned char* Ab = smem + (BUF) * 16384u; \
    const unsigned char* Bb = smem + 32768u + (BUF) * 4096u; \
    const int fr = lane & 15, k16 = (lane >> 4) << 4; \
    _Pragma("unroll") for (int kk = 0; kk < 2; ++kk) { \
      short8 a[2], bfr; \
      _Pragma("unroll") for (int i = 0; i < 2; ++i) { \
        const int rw = (wm << 5) + (i << 4) + fr; \
        a[i] = *(const short8*)(Ab + (((rw << 7) + (kk << 6) + k16) ^ ((rw & 7) << 4))); \
      } \
      { const int rw = (wn << 4) + fr; \
        bfr = *(const short8*)(Bb + (((rw << 7) + (kk << 6) + k16) ^ ((rw & 7) << 4))); } \
      _Pragma("unroll") for (int i = 0; i < 2; ++i) \
        acc[i] = __builtin_amdgcn_mfma_f32_16x16x32_bf16(a[i], bfr, acc[i], 0, 0, 0); \
    } } while (0)

  // STEP invariant at entry: in-flight = B(KT+1) (1 load).
#define STEP(CUR, NXT, PBP, PBN, KT) do { \
    GLA(NXT, (KT) + 1);     /* 2 */ \
    BLOAD(PBN, (KT) + 2);   /* 1 */ \
    COMP(CUR); \
    WAITVM(1);   /* drain GLA+B(KT+1); keep B(KT+2) */ \
    BSTORE(NXT, PBP); \
    sync_ds(); } while (0)

  GLA(0, 0);
  BLOAD(pbA, 0);
  BLOAD(pbB, 1);
  WAITVM(1);
  BSTORE(0, pbA);
  sync_ds();

#pragma unroll
  for (int kt = 0; kt < 14; kt += 2) {
    STEP(0, 1, pbB, pbA, kt);
    STEP(1, 0, pbA, pbB, kt + 1);
  }
  GLA(1, 15);
  COMP(0);            // tile 14
  WAITVM(0);
  BSTORE(1, pbB);
  sync_ds();
  COMP(1);            // tile 15

  const int col16 = lane & 15, row4 = (lane >> 4) << 2;
  unsigned short* outp = part + (size_t)s * BATCH * 1024;
#pragma unroll
  for (int i = 0; i < 2; ++i)
#pragma unroll
    for (int r = 0; r < 4; ++r)
      outp[(size_t)((mh << 7) + (wm << 5) + (i << 4) + row4 + r) * 1024
           + n0 + (wn << 4) + col16] = f2bf(acc[i][r]);
#undef STEP
#undef COMP
#undef GLA
#undef BLOAD
#undef BSTORE
}

// ---------------------------------------------------------------------------
// K4: fused head (bf16 partials). One block per batch row, 512 threads.
// ---------------------------------------------------------------------------
__global__ __launch_bounds__(512) void k4_head(
    const unsigned short* __restrict__ part,   // [16][256][1024] bf16
    const float* __restrict__ b1,
    const float* __restrict__ w2,
    const float* __restrict__ b2,
    float* __restrict__ out)
{
  const int b = blockIdx.x;
  const int t = threadIdx.x;
  const int n0 = t << 1;
  float s0 = b1[n0], s1 = b1[n0 + 1];
#pragma unroll
  for (int sp = 0; sp < SPLIT; ++sp) {
    const unsigned u = *(const unsigned*)(part + ((size_t)sp * BATCH + b) * 1024 + n0);
    union { unsigned u; float f; } lo, hi;
    lo.u = u << 16;
    hi.u = u & 0xffff0000u;
    s0 += lo.f;
    s1 += hi.f;
  }
  float accum = fmaxf(s0, 0.0f) * w2[n0] + fmaxf(s1, 0.0f) * w2[n0 + 1];
  __shared__ float red[8];
#pragma unroll
  for (int off = 32; off > 0; off >>= 1)
    accum += __shfl_down(accum, off);
  if ((t & 63) == 0) red[t >> 6] = accum;
  __syncthreads();
  if (t == 0) {
    float r = b2[0];
#pragma unroll
    for (int w = 0; w < 8; ++w) r += red[w];
    out[b] = r;
  }
}

// ---------------------------------------------------------------------------
extern "C" void kernel_launch(void* const* d_in, const int* in_sizes, int n_in,
                              void* d_out, int out_size, void* d_ws, size_t ws_size,
                              hipStream_t stream) {
  const float* inputs = (const float*)d_in[0];
  const float* W_ih   = (const float*)d_in[1];
  // d_in[2] = W_hh: unused (h0 == 0)
  const float* b_ih   = (const float*)d_in[3];
  const float* b_hh   = (const float*)d_in[4];
  const float* imp    = (const float*)d_in[5];
  const float* m1w    = (const float*)d_in[6];
  const float* m1b    = (const float*)d_in[7];
  const float* m2w    = (const float*)d_in[8];
  const float* m2b    = (const float*)d_in[9];
  float* out = (float*)d_out;

  char* ws = (char*)d_ws;
  unsigned short* aggT = (unsigned short*)ws;                // 8 MB tiled bf16
  unsigned short* part = (unsigned short*)(ws + (8u << 20)); // 8 MB bf16

  k1_gates<<<dim3(1024), 512, 0, stream>>>(inputs, W_ih, b_ih, b_hh, imp, aggT);
  k3_mlp1 <<<dim3(1024), 512, 0, stream>>>(aggT, m1w, part);
  k4_head <<<dim3(256), 512, 0, stream>>>(part, m1b, m2w, m2b, out);
}

// Round 10
// 84.922 us; speedup vs baseline: 1.5371x; 1.0010x over previous
//
#include <hip/hip_runtime.h>
#include <hip/hip_bf16.h>
#include <stdint.h>

#define NVAR 32
#define LAGD 1024
#define BATCH 256
#define HDIM 512
#define SPLIT 16

typedef __attribute__((ext_vector_type(4))) float f32x4;
typedef __attribute__((ext_vector_type(8))) short short8;
typedef __attribute__((ext_vector_type(4))) unsigned short us4;
typedef __attribute__((ext_vector_type(8))) unsigned short us8;

__device__ __forceinline__ unsigned short f2bf(float f) {
  union { __hip_bfloat16 b; unsigned short s; } cv;
  cv.b = __float2bfloat16(f);
  return cv.s;
}
__device__ __forceinline__ us8 cvt8(f32x4 a, f32x4 b) {
  us8 u;
#pragma unroll
  for (int e = 0; e < 4; ++e) { u[e] = f2bf(a[e]); u[4 + e] = f2bf(b[e]); }
  return u;
}

// global -> LDS direct copy, 16 B per lane (dest = wave-uniform base + lane*16).
__device__ __forceinline__ void gload16(const void* g, const void* l) {
  __builtin_amdgcn_global_load_lds(
      (const __attribute__((address_space(1))) unsigned int*)(uintptr_t)g,
      (__attribute__((address_space(3))) unsigned int*)(unsigned int)(uintptr_t)l,
      16, 0, 0);
}

// Order-pinned global load (asm volatile keeps FIFO position).
__device__ __forceinline__ f32x4 gldx4(const float* p) {
  f32x4 r;
  asm volatile("global_load_dwordx4 %0, %1, off" : "=v"(r) : "v"(p) : "memory");
  return r;
}

#define WAITVM(N) do { \
    asm volatile("s_waitcnt vmcnt(" #N ")" ::: "memory"); \
    __builtin_amdgcn_sched_barrier(0); } while (0)

__device__ __forceinline__ void sync_ds() {
  asm volatile("s_waitcnt lgkmcnt(0)" ::: "memory");
  __builtin_amdgcn_s_barrier();
}

// ---------------------------------------------------------------------------
// K1: gates GEMM + LSTM activation.  BM=256, 32 K-steps of 32.
//   A (X, L2/L3-hot): reg-staged 2 steps ahead (pa0/pa1), LDS dbuf 2x16K.
//   B (W, HBM stream): K=128 groups -> 512 B contiguous per row per visit
//   (page-burst), reg depth: issued 4 steps before use. LDS dbuf 2x16K.
//   64 KB LDS -> 2 blocks/CU. Compile-time exact vmcnt counts.
// ---------------------------------------------------------------------------
__global__ __launch_bounds__(512, 4) void k1_gates(
    const float* __restrict__ X,          // [256][32][1024]
    const float* __restrict__ W,          // [32][2048][1024]
    const float* __restrict__ b_ih,
    const float* __restrict__ b_hh,
    const float* __restrict__ imp,
    unsigned short* __restrict__ aggT)    // [32 v][16 kt][256][32] swizzled bf16
{
  const int bid = blockIdx.x;
  const int chunk = ((bid & 7) << 6) | (bid >> 3);   // XCD-contiguous
  const int v = chunk >> 4;
  const int h0 = (chunk & 15) << 5;

  const int t = threadIdx.x, lane = t & 63, wave = t >> 6;
  const int wm = wave & 3, wh = wave >> 2;

  __shared__ __align__(16) unsigned char smem[65536]; // A:2x16K @0, B:2x16K @32768

  // A: thread owns row rt (0..255), 16 contiguous floats at ch*16
  const int rt = t >> 1, ch = t & 1;
  const float* Asrc = X + (size_t)rt * (NVAR * LAGD) + (size_t)v * LAGD + ch * 16;
  const unsigned asw = (unsigned)((rt & 7) << 4);
  const unsigned ab0 = (unsigned)((rt << 6) + (ch << 5));

  // B: thread owns row br (0..63: 32 i + 32 g), 16 contiguous floats
  const int br = t >> 3;
  const int wrow = (br < 32) ? (h0 + br) : (1024 + h0 + br - 32);
  const float* Bsrc = W + (size_t)v * (2048 * LAGD) + (size_t)wrow * LAGD + ((t & 7) << 4);
  const unsigned bsw = (unsigned)((br & 7) << 4);
  const unsigned bb0 = (unsigned)((br << 8) + ((t & 7) << 5));

  f32x4 acc_i[4] = {}, acc_g[4] = {};
  f32x4 pa0[4], pa1[4], pb[4];

#define ALOAD(PA, SS) do { \
    _Pragma("unroll") for (int _e = 0; _e < 4; ++_e) \
      (PA)[_e] = gldx4(Asrc + (SS) * 32 + _e * 4); } while (0)

#define ASTORE(BUF, PA) do { \
    *(us8*)(smem + (BUF) * 16384u + (ab0 ^ asw))        = cvt8((PA)[0], (PA)[1]); \
    *(us8*)(smem + (BUF) * 16384u + ((ab0 + 16) ^ asw)) = cvt8((PA)[2], (PA)[3]); } while (0)

#define BGLOAD(G) do { \
    _Pragma("unroll") for (int _e = 0; _e < 4; ++_e) \
      pb[_e] = gldx4(Bsrc + (G) * 128 + _e * 4); } while (0)

#define BSTORE(BUF) do { \
    *(us8*)(smem + 32768u + (BUF) * 16384u + (bb0 ^ bsw))        = cvt8(pb[0], pb[1]); \
    *(us8*)(smem + 32768u + (BUF) * 16384u + ((bb0 + 16) ^ bsw)) = cvt8(pb[2], pb[3]); } while (0)

#define COMP(SS) do { \
    const unsigned char* Ab = smem + ((SS) & 1) * 16384u; \
    const unsigned char* Bb = smem + 32768u + (((SS) >> 2) & 1) * 16384u; \
    const int bk = ((SS) & 3) << 6; \
    const int fr = lane & 15, k16 = (lane >> 4) << 4; \
    short8 a[4], fi, fg; \
    _Pragma("unroll") for (int i = 0; i < 4; ++i) { \
      const int rw = (wm << 6) + (i << 4) + fr; \
      a[i] = *(const short8*)(Ab + (((rw << 6) + k16) ^ ((rw & 7) << 4))); \
    } \
    { const int rw = (wh << 4) + fr; \
      fi = *(const short8*)(Bb + (((rw << 8) + bk + k16) ^ ((rw & 7) << 4))); \
      fg = *(const short8*)(Bb + ((((rw + 32) << 8) + bk + k16) ^ ((rw & 7) << 4))); } \
    _Pragma("unroll") for (int i = 0; i < 4; ++i) { \
      acc_i[i] = __builtin_amdgcn_mfma_f32_16x16x32_bf16(a[i], fi, acc_i[i], 0, 0, 0); \
      acc_g[i] = __builtin_amdgcn_mfma_f32_16x16x32_bf16(a[i], fg, acc_g[i], 0, 0, 0); } \
  } while (0)

  // prologue: A(0),A(1) regs; B group 0; store A0 + B0; full drain once.
  ALOAD(pa0, 0);
  ALOAD(pa1, 1);
  BGLOAD(0);
  WAITVM(0);
  ASTORE(0, pa0);
  BSTORE(0);
  sync_ds();

#pragma unroll
  for (int ss = 0; ss < 32; ++ss) {
    if (ss <= 29) { if ((ss & 1) == 0) ALOAD(pa0, ss + 2); else ALOAD(pa1, ss + 2); }
    if ((ss & 3) == 0 && ss <= 24) BGLOAD((ss >> 2) + 1);
    COMP(ss);
    // drain A(ss+1) (oldest); keep fresh B group + A(ss+2)
    if (ss <= 27) { if ((ss & 3) <= 1) WAITVM(8); else WAITVM(4); }
    else if (ss <= 29) WAITVM(4);
    else if (ss == 30) WAITVM(0);
    if (ss <= 30) { if ((ss & 1) == 0) ASTORE((ss + 1) & 1, pa1); else ASTORE((ss + 1) & 1, pa0); }
    if ((ss & 3) == 3 && ss <= 27) BSTORE(((ss + 1) >> 2) & 1);
    if (ss <= 30) sync_ds();
  }

  // epilogue: c = sigmoid(i+bi)*tanh(g+bg)*imp -> aggT [v][kt][256][32] tiles
  const int col16 = lane & 15, row4 = (lane >> 4) << 2;
  const float impv = imp[v];
  const int h = h0 + (wh << 4) + col16;
  const float bsi = b_ih[v * 2048 + h] + b_hh[v * 2048 + h];
  const float bsg = b_ih[v * 2048 + 1024 + h] + b_hh[v * 2048 + 1024 + h];
  char* obase = (char*)aggT + ((size_t)v * 16 + (h0 >> 5)) * 16384;
  const int hc = h & 31;
#pragma unroll
  for (int i = 0; i < 4; ++i)
#pragma unroll
    for (int r = 0; r < 4; ++r) {
      const int m = (wm << 6) + (i << 4) + row4 + r;
      const float ii = acc_i[i][r] + bsi;
      const float gg = acc_g[i][r] + bsg;
      const float c = (1.0f / (1.0f + __expf(-ii))) * tanhf(gg) * impv;
      *(unsigned short*)(obase + (((m << 6) + (hc << 1)) ^ ((m & 7) << 4))) = f2bf(c);
    }
#undef COMP
#undef ALOAD
#undef ASTORE
#undef BGLOAD
#undef BSTORE
}

// ---------------------------------------------------------------------------
// K3: mlp1 split-K GEMM.  BM=256, BN=32, Kslice=1024 -> 32 K-steps of 32.
//   A (aggT tiles, L2-hot): gload_lds, TRIPLE buffer (2 steps ahead).
//   B (m1w, HBM stream): K=256 groups -> 1 KB contiguous per row per visit.
//   80 KB LDS -> 2 blocks/CU.
// ---------------------------------------------------------------------------
__global__ __launch_bounds__(512, 4) void k3_mlp1(
    const unsigned short* __restrict__ aggT,  // [32 v][16 kt][256][32] tiles
    const float* __restrict__ Wm,             // [1024][16384]
    unsigned short* __restrict__ part)        // [16][256][1024] bf16
{
  const int bid = blockIdx.x;
  const int chunk = ((bid & 7) << 6) | (bid >> 3);
  const int s  = chunk >> 5;                 // 0..15
  const int n0 = (chunk & 31) << 5;          // 0..992

  const int t = threadIdx.x, lane = t & 63, wave = t >> 6;
  const int wm = wave & 3, wn = wave >> 2;

  __shared__ __align__(16) unsigned char smem[81920]; // A:3x16K @0, B:2x16K @49152

  const char* Abase = (const char*)aggT;
  const unsigned athr = (unsigned)(wave * 2048 + lane * 16);

  // B: thread owns row br (0..31), 16 contiguous floats at (t&15)*16
  const int br = t >> 4;
  const float* Bsrc = Wm + (size_t)(n0 + br) * 16384 + (size_t)s * 1024 + ((t & 15) << 4);
  const unsigned bsw = (unsigned)((br & 7) << 4);
  const unsigned bb0 = (unsigned)((br << 9) + ((t & 15) << 5));

  f32x4 acc[4] = {};
  f32x4 pb[4];

#define GLA(SS) do { \
    const int _tile = (2 * s + ((SS) >= 16)) * 16 + ((SS) & 15); \
    _Pragma("unroll") for (int _r = 0; _r < 2; ++_r) \
      gload16(Abase + (size_t)_tile * 16384 + athr + _r * 1024, \
              smem + ((SS) % 3) * 16384u + wave * 2048u + _r * 1024u); } while (0)

#define BGLOAD(G) do { \
    _Pragma("unroll") for (int _e = 0; _e < 4; ++_e) \
      pb[_e] = gldx4(Bsrc + (G) * 256 + _e * 4); } while (0)

#define BSTORE(BUF) do { \
    *(us8*)(smem + 49152u + (BUF) * 16384u + (bb0 ^ bsw))        = cvt8(pb[0], pb[1]); \
    *(us8*)(smem + 49152u + (BUF) * 16384u + ((bb0 + 16) ^ bsw)) = cvt8(pb[2], pb[3]); } while (0)

#define COMP(SS) do { \
    const unsigned char* Ab = smem + ((SS) % 3) * 16384u; \
    const unsigned char* Bb = smem + 49152u + (((SS) >> 3) & 1) * 16384u; \
    const int bk = ((SS) & 7) << 6; \
    const int fr = lane & 15, k16 = (lane >> 4) << 4; \
    short8 a[4], bf; \
    _Pragma("unroll") for (int i = 0; i < 4; ++i) { \
      const int rw = (wm << 6) + (i << 4) + fr; \
      a[i] = *(const short8*)(Ab + (((rw << 6) + k16) ^ ((rw & 7) << 4))); \
    } \
    { const int rw = (wn << 4) + fr; \
      bf = *(const short8*)(Bb + (((rw << 9) + bk + k16) ^ ((rw & 7) << 4))); } \
    _Pragma("unroll") for (int i = 0; i < 4; ++i) \
      acc[i] = __builtin_amdgcn_mfma_f32_16x16x32_bf16(a[i], bf, acc[i], 0, 0, 0); \
  } while (0)

  // prologue: tiles 0,1 staged; B group 0; full drain once.
  GLA(0);
  GLA(1);
  BGLOAD(0);
  WAITVM(0);
  BSTORE(0);
  sync_ds();

#pragma unroll
  for (int ss = 0; ss < 32; ++ss) {
    if (ss <= 29) GLA(ss + 2);
    if ((ss == 0) | (ss == 8) | (ss == 16)) BGLOAD((ss >> 3) + 1);
    COMP(ss);
    if (ss <= 23 && (ss & 7) <= 1) WAITVM(6);
    else if (ss <= 29) WAITVM(2);
    else if (ss == 30) WAITVM(0);
    if ((ss & 7) == 7 && ss <= 23) BSTORE(((ss + 1) >> 3) & 1);
    if (ss <= 30) sync_ds();
  }

  const int col16 = lane & 15, row4 = (lane >> 4) << 2;
  unsigned short* outp = part + (size_t)s * BATCH * 1024;
#pragma unroll
  for (int i = 0; i < 4; ++i)
#pragma unroll
    for (int r = 0; r < 4; ++r)
      outp[(size_t)((wm << 6) + (i << 4) + row4 + r) * 1024
           + n0 + (wn << 4) + col16] = f2bf(acc[i][r]);
#undef COMP
#undef GLA
#undef BGLOAD
#undef BSTORE
}

// ---------------------------------------------------------------------------
// K4: fused head (bf16 partials). One block per batch row, 512 threads.
// ---------------------------------------------------------------------------
__global__ __launch_bounds__(512) void k4_head(
    const unsigned short* __restrict__ part,   // [16][256][1024] bf16
    const float* __restrict__ b1,
    const float* __restrict__ w2,
    const float* __restrict__ b2,
    float* __restrict__ out)
{
  const int b = blockIdx.x;
  const int t = threadIdx.x;
  const int n0 = t << 1;
  float s0 = b1[n0], s1 = b1[n0 + 1];
#pragma unroll
  for (int sp = 0; sp < SPLIT; ++sp) {
    const unsigned u = *(const unsigned*)(part + ((size_t)sp * BATCH + b) * 1024 + n0);
    union { unsigned u; float f; } lo, hi;
    lo.u = u << 16;
    hi.u = u & 0xffff0000u;
    s0 += lo.f;
    s1 += hi.f;
  }
  float accum = fmaxf(s0, 0.0f) * w2[n0] + fmaxf(s1, 0.0f) * w2[n0 + 1];
  __shared__ float red[8];
#pragma unroll
  for (int off = 32; off > 0; off >>= 1)
    accum += __shfl_down(accum, off);
  if ((t & 63) == 0) red[t >> 6] = accum;
  __syncthreads();
  if (t == 0) {
    float r = b2[0];
#pragma unroll
    for (int w = 0; w < 8; ++w) r += red[w];
    out[b] = r;
  }
}

// ---------------------------------------------------------------------------
extern "C" void kernel_launch(void* const* d_in, const int* in_sizes, int n_in,
                              void* d_out, int out_size, void* d_ws, size_t ws_size,
                              hipStream_t stream) {
  const float* inputs = (const float*)d_in[0];
  const float* W_ih   = (const float*)d_in[1];
  // d_in[2] = W_hh: unused (h0 == 0)
  const float* b_ih   = (const float*)d_in[3];
  const float* b_hh   = (const float*)d_in[4];
  const float* imp    = (const float*)d_in[5];
  const float* m1w    = (const float*)d_in[6];
  const float* m1b    = (const float*)d_in[7];
  const float* m2w    = (const float*)d_in[8];
  const float* m2b    = (const float*)d_in[9];
  float* out = (float*)d_out;

  char* ws = (char*)d_ws;
  unsigned short* aggT = (unsigned short*)ws;                // 8 MB tiled bf16
  unsigned short* part = (unsigned short*)(ws + (8u << 20)); // 8 MB bf16

  k1_gates<<<dim3(512), 512, 0, stream>>>(inputs, W_ih, b_ih, b_hh, imp, aggT);
  k3_mlp1 <<<dim3(512), 512, 0, stream>>>(aggT, m1w, part);
  k4_head <<<dim3(256), 512, 0, stream>>>(part, m1b, m2w, m2b, out);
}

// Round 11
// 77.447 us; speedup vs baseline: 1.6855x; 1.0965x over previous
//
#include <hip/hip_runtime.h>
#include <hip/hip_bf16.h>
#include <stdint.h>

#define NVAR 32
#define LAGD 1024
#define BATCH 256
#define HDIM 512
#define SPLIT 16

typedef __attribute__((ext_vector_type(4))) float f32x4;
typedef __attribute__((ext_vector_type(2))) float f32x2;
typedef __attribute__((ext_vector_type(8))) short short8;
typedef __attribute__((ext_vector_type(4))) unsigned short us4;
typedef __attribute__((ext_vector_type(8))) unsigned short us8;

__device__ __forceinline__ unsigned short f2bf(float f) {
  union { __hip_bfloat16 b; unsigned short s; } cv;
  cv.b = __float2bfloat16(f);
  return cv.s;
}
__device__ __forceinline__ us8 cvt8(f32x4 a, f32x4 b) {
  us8 u;
#pragma unroll
  for (int e = 0; e < 4; ++e) { u[e] = f2bf(a[e]); u[4 + e] = f2bf(b[e]); }
  return u;
}
__device__ __forceinline__ us4 cvt4(f32x4 a) {
  us4 u;
#pragma unroll
  for (int e = 0; e < 4; ++e) u[e] = f2bf(a[e]);
  return u;
}

// global -> LDS direct copy, 16 B per lane (dest = wave-uniform base + lane*16).
__device__ __forceinline__ void gload16(const void* g, const void* l) {
  __builtin_amdgcn_global_load_lds(
      (const __attribute__((address_space(1))) unsigned int*)(uintptr_t)g,
      (__attribute__((address_space(3))) unsigned int*)(unsigned int)(uintptr_t)l,
      16, 0, 0);
}

// Order-pinned global load (asm volatile keeps FIFO position).
__device__ __forceinline__ f32x4 gldx4(const float* p) {
  f32x4 r;
  asm volatile("global_load_dwordx4 %0, %1, off" : "=v"(r) : "v"(p) : "memory");
  return r;
}

#define WAITVM(N) do { \
    asm volatile("s_waitcnt vmcnt(" #N ")" ::: "memory"); \
    __builtin_amdgcn_sched_barrier(0); } while (0)

__device__ __forceinline__ void sync_ds() {
  asm volatile("s_waitcnt lgkmcnt(0)" ::: "memory");
  __builtin_amdgcn_s_barrier();
}

// ---------------------------------------------------------------------------
// K1: gates GEMM + LSTM activation (round-6 structure, proven 2 blocks/CU,
//   BK=64, counted-vmcnt FIFO). Also zeroes the mlp1 accumulator (1 float
//   per thread) so K3 can atomicAdd into it — no extra launch.
// ---------------------------------------------------------------------------
__global__ __launch_bounds__(512, 4) void k1_gates(
    const float* __restrict__ X,          // [256][32][1024]
    const float* __restrict__ W,          // [32][2048][1024]
    const float* __restrict__ b_ih,
    const float* __restrict__ b_hh,
    const float* __restrict__ imp,
    unsigned short* __restrict__ aggT,    // [32 v][8 kt][256][64] swizzled bf16
    float* __restrict__ accum)            // [256][1024] fp32, zeroed here
{
  const int bid = blockIdx.x;
  const int chunk = ((bid & 7) << 6) | (bid >> 3);   // XCD-contiguous
  const int v = chunk >> 4;
  const int h0 = (chunk & 15) << 5;

  const int t = threadIdx.x, lane = t & 63, wave = t >> 6;
  const int wm = wave & 3, wh = wave >> 2;

  // zero the K3 accumulator: 512 blocks x 512 threads x 1 float = 1 MB
  accum[(bid << 9) | t] = 0.0f;

  __shared__ __align__(16) unsigned char smem[81920]; // A:2x32K @0, B:2x8K @65536

  const int rt = t >> 3, c8 = (t & 7) << 3;
  const float* Asrc = X + (size_t)rt * (NVAR * LAGD) + (size_t)v * LAGD + c8;
  const unsigned awoff = (unsigned)(((rt << 7) + (c8 << 1)) ^ ((rt & 7) << 4));

  const int brow = t >> 3;
  const int wrow = (brow < 32) ? (h0 + brow) : (1024 + h0 + brow - 32);
  const float* Bsrc = W + (size_t)v * (2048 * LAGD) + (size_t)wrow * LAGD + ((t & 7) << 3);
  const unsigned bwoff = (unsigned)(((brow << 7) + ((t & 7) << 4)) ^ ((brow & 7) << 4));

  f32x4 acc_i[4] = {}, acc_g[4] = {};
  f32x4 pa[4][2], pbA[2], pbB[2];

#define ALOAD(KT) do { \
    _Pragma("unroll") for (int _p = 0; _p < 4; ++_p) { \
      pa[_p][0] = gldx4(Asrc + (size_t)_p * 64 * (NVAR * LAGD) + (KT) * 64); \
      pa[_p][1] = gldx4(Asrc + (size_t)_p * 64 * (NVAR * LAGD) + (KT) * 64 + 4); \
    } } while (0)

#define ASTORE(BUF) do { \
    _Pragma("unroll") for (int _p = 0; _p < 4; ++_p) \
      *(us8*)(smem + (BUF) * 32768u + awoff + _p * 8192u) = cvt8(pa[_p][0], pa[_p][1]); \
  } while (0)

#define BLOAD(PB, KT) do { \
    (PB)[0] = gldx4(Bsrc + (KT) * 64); \
    (PB)[1] = gldx4(Bsrc + (KT) * 64 + 4); } while (0)

#define BSTORE(BUF, PB) \
    *(us8*)(smem + 65536u + (BUF) * 8192u + bwoff) = cvt8((PB)[0], (PB)[1])

#define COMP(BUF) do { \
    const unsigned char* Ab = smem + (BUF) * 32768u; \
    const unsigned char* Bb = smem + 65536u + (BUF) * 8192u; \
    const int fr = lane & 15, k16 = (lane >> 4) << 4; \
    _Pragma("unroll") for (int kk = 0; kk < 2; ++kk) { \
      short8 a[4], fi, fg; \
      _Pragma("unroll") for (int i = 0; i < 4; ++i) { \
        const int rw = (wm << 6) + (i << 4) + fr; \
        a[i] = *(const short8*)(Ab + (((rw << 7) + (kk << 6) + k16) ^ ((rw & 7) << 4))); \
      } \
      { const int rw = (wh << 4) + fr; \
        fi = *(const short8*)(Bb + (((rw << 7) + (kk << 6) + k16) ^ ((rw & 7) << 4))); \
        fg = *(const short8*)(Bb + ((((rw + 32) << 7) + (kk << 6) + k16) ^ ((rw & 7) << 4))); } \
      _Pragma("unroll") for (int i = 0; i < 4; ++i) { \
        acc_i[i] = __builtin_amdgcn_mfma_f32_16x16x32_bf16(a[i], fi, acc_i[i], 0, 0, 0); \
        acc_g[i] = __builtin_amdgcn_mfma_f32_16x16x32_bf16(a[i], fg, acc_g[i], 0, 0, 0); } \
    } } while (0)

#define STEP(CUR, NXT, PBP, PBN, KT) do { \
    ALOAD((KT) + 1); \
    BLOAD(PBN, (KT) + 2); \
    COMP(CUR); \
    WAITVM(2); \
    ASTORE(NXT); \
    BSTORE(NXT, PBP); \
    sync_ds(); } while (0)

  ALOAD(0);
  BLOAD(pbA, 0);
  BLOAD(pbB, 1);
  WAITVM(2);
  ASTORE(0);
  BSTORE(0, pbA);
  sync_ds();

#pragma unroll
  for (int kt = 0; kt < 14; kt += 2) {
    STEP(0, 1, pbB, pbA, kt);
    STEP(1, 0, pbA, pbB, kt + 1);
  }
  ALOAD(15);
  COMP(0);
  WAITVM(0);
  ASTORE(1);
  BSTORE(1, pbB);
  sync_ds();
  COMP(1);

  const int col16 = lane & 15, row4 = (lane >> 4) << 2;
  const float impv = imp[v];
  const int h = h0 + (wh << 4) + col16;
  const float bsi = b_ih[v * 2048 + h] + b_hh[v * 2048 + h];
  const float bsg = b_ih[v * 2048 + 1024 + h] + b_hh[v * 2048 + 1024 + h];
  char* obase = (char*)aggT + ((size_t)v * 8 + (h >> 6)) * 32768;
  const int hc = h & 63;
#pragma unroll
  for (int i = 0; i < 4; ++i)
#pragma unroll
    for (int r = 0; r < 4; ++r) {
      const int m = (wm << 6) + (i << 4) + row4 + r;
      const float ii = acc_i[i][r] + bsi;
      const float gg = acc_g[i][r] + bsg;
      const float c = (1.0f / (1.0f + __expf(-ii))) * tanhf(gg) * impv;
      *(unsigned short*)(obase + (((m << 7) + (hc << 1)) ^ ((m & 7) << 4))) = f2bf(c);
    }
#undef STEP
#undef COMP
#undef ALOAD
#undef ASTORE
#undef BLOAD
#undef BSTORE
}

// ---------------------------------------------------------------------------
// K3: mlp1 split-K GEMM (round-6 structure). Epilogue: fp32 atomicAdd into
//   the 1 MB accumulator (L2-resident) — eliminates the part round-trip.
// ---------------------------------------------------------------------------
__global__ __launch_bounds__(512, 4) void k3_mlp1(
    const unsigned short* __restrict__ aggT,
    const float* __restrict__ Wm,          // [1024][16384]
    float* __restrict__ accum)             // [256][1024] fp32
{
  const int bid = blockIdx.x;
  const int chunk = ((bid & 7) << 6) | (bid >> 3);
  const int s = chunk >> 5;                 // 0..15
  const int n0 = (chunk & 31) << 5;         // 0..992

  const int t = threadIdx.x, lane = t & 63, wave = t >> 6;
  const int wm = wave & 3, wn = wave >> 2;

  __shared__ __align__(16) unsigned char smem[73728];

  const char* Asrc = (const char*)aggT + (size_t)s * 16 * 32768 + wave * 1024 + lane * 16;
  const unsigned aoff = wave * 1024u;

  const int brow = t >> 4;
  const int bcol = (t & 15) << 2;
  const float* Bsrc = Wm + (size_t)(n0 + brow) * 16384 + (size_t)s * 1024 + bcol;
  const unsigned bwoff = (unsigned)(((brow << 7) + (bcol << 1)) ^ ((brow & 7) << 4));

  f32x4 acc[4] = {};
  f32x4 pbA, pbB;

#define GLA(BUF, KT) do { \
    _Pragma("unroll") for (int _r = 0; _r < 4; ++_r) \
      gload16(Asrc + (KT) * 32768 + _r * 8192, \
              smem + (BUF) * 32768u + aoff + _r * 8192); } while (0)

#define BLOAD(PB, KT) (PB) = gldx4(Bsrc + (KT) * 64)

#define BSTORE(BUF, PB) \
    *(us4*)(smem + 65536u + (BUF) * 4096u + bwoff) = cvt4(PB)

#define COMP(BUF) do { \
    const unsigned char* Ab = smem + (BUF) * 32768u; \
    const unsigned char* Bb = smem + 65536u + (BUF) * 4096u; \
    const int fr = lane & 15, k16 = (lane >> 4) << 4; \
    _Pragma("unroll") for (int kk = 0; kk < 2; ++kk) { \
      short8 a[4], bfr; \
      _Pragma("unroll") for (int i = 0; i < 4; ++i) { \
        const int rw = (wm << 6) + (i << 4) + fr; \
        a[i] = *(const short8*)(Ab + (((rw << 7) + (kk << 6) + k16) ^ ((rw & 7) << 4))); \
      } \
      { const int rw = (wn << 4) + fr; \
        bfr = *(const short8*)(Bb + (((rw << 7) + (kk << 6) + k16) ^ ((rw & 7) << 4))); } \
      _Pragma("unroll") for (int i = 0; i < 4; ++i) \
        acc[i] = __builtin_amdgcn_mfma_f32_16x16x32_bf16(a[i], bfr, acc[i], 0, 0, 0); \
    } } while (0)

#define STEP(CUR, NXT, PBP, PBN, KT) do { \
    GLA(NXT, (KT) + 1); \
    BLOAD(PBN, (KT) + 2); \
    COMP(CUR); \
    WAITVM(1); \
    BSTORE(NXT, PBP); \
    sync_ds(); } while (0)

  GLA(0, 0);
  BLOAD(pbA, 0);
  BLOAD(pbB, 1);
  WAITVM(1);
  BSTORE(0, pbA);
  sync_ds();

#pragma unroll
  for (int kt = 0; kt < 14; kt += 2) {
    STEP(0, 1, pbB, pbA, kt);
    STEP(1, 0, pbA, pbB, kt + 1);
  }
  GLA(1, 15);
  COMP(0);
  WAITVM(0);
  BSTORE(1, pbB);
  sync_ds();
  COMP(1);

  const int col16 = lane & 15, row4 = (lane >> 4) << 2;
  const int n = n0 + (wn << 4) + col16;
#pragma unroll
  for (int i = 0; i < 4; ++i)
#pragma unroll
    for (int r = 0; r < 4; ++r) {
      const int m = (wm << 6) + (i << 4) + row4 + r;
      unsafeAtomicAdd(&accum[(size_t)m * 1024 + n], acc[i][r]);
    }
#undef STEP
#undef COMP
#undef GLA
#undef BLOAD
#undef BSTORE
}

// ---------------------------------------------------------------------------
// K4: head. accum is fully reduced fp32; bias + relu + dot with w2.
// ---------------------------------------------------------------------------
__global__ __launch_bounds__(512) void k4_head(
    const float* __restrict__ accum,   // [256][1024] fp32
    const float* __restrict__ b1,
    const float* __restrict__ w2,
    const float* __restrict__ b2,
    float* __restrict__ out)
{
  const int b = blockIdx.x;
  const int t = threadIdx.x;
  const int n0 = t << 1;
  const f32x2 a = *(const f32x2*)(accum + (size_t)b * 1024 + n0);
  const float s0 = b1[n0] + a[0];
  const float s1 = b1[n0 + 1] + a[1];
  float dot = fmaxf(s0, 0.0f) * w2[n0] + fmaxf(s1, 0.0f) * w2[n0 + 1];
  __shared__ float red[8];
#pragma unroll
  for (int off = 32; off > 0; off >>= 1)
    dot += __shfl_down(dot, off);
  if ((t & 63) == 0) red[t >> 6] = dot;
  __syncthreads();
  if (t == 0) {
    float r = b2[0];
#pragma unroll
    for (int w = 0; w < 8; ++w) r += red[w];
    out[b] = r;
  }
}

// ---------------------------------------------------------------------------
extern "C" void kernel_launch(void* const* d_in, const int* in_sizes, int n_in,
                              void* d_out, int out_size, void* d_ws, size_t ws_size,
                              hipStream_t stream) {
  const float* inputs = (const float*)d_in[0];
  const float* W_ih   = (const float*)d_in[1];
  // d_in[2] = W_hh: unused (h0 == 0)
  const float* b_ih   = (const float*)d_in[3];
  const float* b_hh   = (const float*)d_in[4];
  const float* imp    = (const float*)d_in[5];
  const float* m1w    = (const float*)d_in[6];
  const float* m1b    = (const float*)d_in[7];
  const float* m2w    = (const float*)d_in[8];
  const float* m2b    = (const float*)d_in[9];
  float* out = (float*)d_out;

  char* ws = (char*)d_ws;
  unsigned short* aggT = (unsigned short*)ws;          // 8 MB tiled bf16
  float* accum         = (float*)(ws + (8u << 20));    // 1 MB fp32

  k1_gates<<<dim3(512), 512, 0, stream>>>(inputs, W_ih, b_ih, b_hh, imp, aggT, accum);
  k3_mlp1 <<<dim3(512), 512, 0, stream>>>(aggT, m1w, accum);
  k4_head <<<dim3(256), 512, 0, stream>>>(accum, m1b, m2w, m2b, out);
}

// Round 14
// 69.334 us; speedup vs baseline: 1.8827x; 1.1170x over previous
//
#include <hip/hip_runtime.h>
#include <hip/hip_bf16.h>
#include <stdint.h>

#define NVAR 32
#define LAGD 1024
#define BATCH 256
#define HDIM 512
#define SPLIT 16

typedef __attribute__((ext_vector_type(4))) float f32x4;
typedef __attribute__((ext_vector_type(8))) short short8;
typedef __attribute__((ext_vector_type(4))) unsigned short us4;
typedef __attribute__((ext_vector_type(8))) unsigned short us8;

__device__ __forceinline__ unsigned short f2bf(float f) {
  union { __hip_bfloat16 b; unsigned short s; } cv;
  cv.b = __float2bfloat16(f);
  return cv.s;
}
__device__ __forceinline__ us8 cvt8(f32x4 a, f32x4 b) {
  us8 u;
#pragma unroll
  for (int e = 0; e < 4; ++e) { u[e] = f2bf(a[e]); u[4 + e] = f2bf(b[e]); }
  return u;
}
__device__ __forceinline__ us4 cvt4(f32x4 a) {
  us4 u;
#pragma unroll
  for (int e = 0; e < 4; ++e) u[e] = f2bf(a[e]);
  return u;
}

// global -> LDS direct copy, 16 B per lane (dest = wave-uniform base + lane*16).
__device__ __forceinline__ void gload16(const void* g, const void* l) {
  __builtin_amdgcn_global_load_lds(
      (const __attribute__((address_space(1))) unsigned int*)(uintptr_t)g,
      (__attribute__((address_space(3))) unsigned int*)(unsigned int)(uintptr_t)l,
      16, 0, 0);
}

// Order-pinned global load (asm volatile keeps FIFO position).
__device__ __forceinline__ f32x4 gldx4(const float* p) {
  f32x4 r;
  asm volatile("global_load_dwordx4 %0, %1, off" : "=v"(r) : "v"(p) : "memory");
  return r;
}

// Counted vmem wait; sched_barrier stops hipcc hoisting dependent ops above it.
#define WAITVM(N) do { \
    asm volatile("s_waitcnt vmcnt(" #N ")" ::: "memory"); \
    __builtin_amdgcn_sched_barrier(0); } while (0)

// Barrier that does NOT drain vmcnt (prefetch survives across it).
__device__ __forceinline__ void sync_ds() {
  asm volatile("s_waitcnt lgkmcnt(0)" ::: "memory");
  __builtin_amdgcn_s_barrier();
}

// ---------------------------------------------------------------------------
// K1: gates GEMM + LSTM activation, fp32 X staged in-kernel.
//   Block (v, h-tile 32), grid 512, 8 waves, 2 blocks/CU. All 16 h-blocks of
//   a var are co-resident on one XCD (chunk swizzle) -> X tiles L2-hit.
//   A: X fp32 -> reg (depth-1) -> cvt -> swizzled LDS.  B: W fp32 reg depth-2.
//   16 K-tiles of 64, counted-vmcnt FIFO (never drains mid-loop).
// ---------------------------------------------------------------------------
__global__ __launch_bounds__(512, 4) void k1_gates(
    const float* __restrict__ X,          // [256][32][1024]
    const float* __restrict__ W,          // [32][2048][1024]
    const float* __restrict__ b_ih,
    const float* __restrict__ b_hh,
    const float* __restrict__ imp,
    unsigned short* __restrict__ aggT)    // [32 v][8 kt][256][64] swizzled bf16
{
  const int bid = blockIdx.x;
  const int chunk = ((bid & 7) << 6) | (bid >> 3);   // XCD-contiguous
  const int v = chunk >> 4;
  const int h0 = (chunk & 15) << 5;

  const int t = threadIdx.x, lane = t & 63, wave = t >> 6;
  const int wm = wave & 3, wh = wave >> 2;

  __shared__ __align__(16) unsigned char smem[81920]; // A:2x32K @0, B:2x8K @65536

  // A staging: thread owns rows rt+64p (p=0..3), 8 fp32 cols at c8
  const int rt = t >> 3, c8 = (t & 7) << 3;
  const float* Asrc = X + (size_t)rt * (NVAR * LAGD) + (size_t)v * LAGD + c8;
  const unsigned awoff = (unsigned)(((rt << 7) + (c8 << 1)) ^ ((rt & 7) << 4));

  // B staging: 64 rows (32 i + 32 g), 8 fp32 cols per thread
  const int brow = t >> 3;
  const int wrow = (brow < 32) ? (h0 + brow) : (1024 + h0 + brow - 32);
  const float* Bsrc = W + (size_t)v * (2048 * LAGD) + (size_t)wrow * LAGD + ((t & 7) << 3);
  const unsigned bwoff = (unsigned)(((brow << 7) + ((t & 7) << 4)) ^ ((brow & 7) << 4));

  f32x4 acc_i[4] = {}, acc_g[4] = {};
  f32x4 pa[4][2], pbA[2], pbB[2];

#define ALOAD(KT) do { \
    _Pragma("unroll") for (int _p = 0; _p < 4; ++_p) { \
      pa[_p][0] = gldx4(Asrc + (size_t)_p * 64 * (NVAR * LAGD) + (KT) * 64); \
      pa[_p][1] = gldx4(Asrc + (size_t)_p * 64 * (NVAR * LAGD) + (KT) * 64 + 4); \
    } } while (0)

#define ASTORE(BUF) do { \
    _Pragma("unroll") for (int _p = 0; _p < 4; ++_p) \
      *(us8*)(smem + (BUF) * 32768u + awoff + _p * 8192u) = cvt8(pa[_p][0], pa[_p][1]); \
  } while (0)

#define BLOAD(PB, KT) do { \
    (PB)[0] = gldx4(Bsrc + (KT) * 64); \
    (PB)[1] = gldx4(Bsrc + (KT) * 64 + 4); } while (0)

#define BSTORE(BUF, PB) \
    *(us8*)(smem + 65536u + (BUF) * 8192u + bwoff) = cvt8((PB)[0], (PB)[1])

#define COMP(BUF) do { \
    const unsigned char* Ab = smem + (BUF) * 32768u; \
    const unsigned char* Bb = smem + 65536u + (BUF) * 8192u; \
    const int fr = lane & 15, k16 = (lane >> 4) << 4; \
    _Pragma("unroll") for (int kk = 0; kk < 2; ++kk) { \
      short8 a[4], fi, fg; \
      _Pragma("unroll") for (int i = 0; i < 4; ++i) { \
        const int rw = (wm << 6) + (i << 4) + fr; \
        a[i] = *(const short8*)(Ab + (((rw << 7) + (kk << 6) + k16) ^ ((rw & 7) << 4))); \
      } \
      { const int rw = (wh << 4) + fr; \
        fi = *(const short8*)(Bb + (((rw << 7) + (kk << 6) + k16) ^ ((rw & 7) << 4))); \
        fg = *(const short8*)(Bb + ((((rw + 32) << 7) + (kk << 6) + k16) ^ ((rw & 7) << 4))); } \
      _Pragma("unroll") for (int i = 0; i < 4; ++i) { \
        acc_i[i] = __builtin_amdgcn_mfma_f32_16x16x32_bf16(a[i], fi, acc_i[i], 0, 0, 0); \
        acc_g[i] = __builtin_amdgcn_mfma_f32_16x16x32_bf16(a[i], fg, acc_g[i], 0, 0, 0); } \
    } } while (0)

  // STEP invariant at entry: in-flight = B(KT+1) (2 loads).
#define STEP(CUR, NXT, PBP, PBN, KT) do { \
    ALOAD((KT) + 1);        /* 8 loads */ \
    BLOAD(PBN, (KT) + 2);   /* 2 loads */ \
    COMP(CUR); \
    WAITVM(2);   /* drain B(KT+1) + A(KT+1); keep B(KT+2) */ \
    ASTORE(NXT); \
    BSTORE(NXT, PBP); \
    sync_ds(); } while (0)

  // prologue
  ALOAD(0);
  BLOAD(pbA, 0);
  BLOAD(pbB, 1);
  WAITVM(2);          // drain A(0)+pbA; pbB stays
  ASTORE(0);
  BSTORE(0, pbA);
  sync_ds();

#pragma unroll
  for (int kt = 0; kt < 14; kt += 2) {
    STEP(0, 1, pbB, pbA, kt);
    STEP(1, 0, pbA, pbB, kt + 1);
  }
  // tail: buf0 holds tile 14; pbB = B(15) in flight
  ALOAD(15);
  COMP(0);            // tile 14
  WAITVM(0);
  ASTORE(1);
  BSTORE(1, pbB);
  sync_ds();
  COMP(1);            // tile 15

  // epilogue: c = sigmoid(i+bi)*tanh(g+bg)*imp -> aggT (swizzled tile layout)
  const int col16 = lane & 15, row4 = (lane >> 4) << 2;
  const float impv = imp[v];
  const int h = h0 + (wh << 4) + col16;
  const float bsi = b_ih[v * 2048 + h] + b_hh[v * 2048 + h];
  const float bsg = b_ih[v * 2048 + 1024 + h] + b_hh[v * 2048 + 1024 + h];
  char* obase = (char*)aggT + ((size_t)v * 8 + (h >> 6)) * 32768;
  const int hc = h & 63;
#pragma unroll
  for (int i = 0; i < 4; ++i)
#pragma unroll
    for (int r = 0; r < 4; ++r) {
      const int m = (wm << 6) + (i << 4) + row4 + r;
      const float ii = acc_i[i][r] + bsi;
      const float gg = acc_g[i][r] + bsg;
      const float c = (1.0f / (1.0f + __expf(-ii))) * tanhf(gg) * impv;
      *(unsigned short*)(obase + (((m << 7) + (hc << 1)) ^ ((m & 7) << 4))) = f2bf(c);
    }
#undef STEP
#undef COMP
#undef ALOAD
#undef ASTORE
#undef BLOAD
#undef BSTORE
}

// ---------------------------------------------------------------------------
// K3: mlp1 split-K GEMM, SPLIT=16 (Kslice=1024 = vars 2s,2s+1), BN=32.
//   Grid 512 (2 blocks/CU). A: aggT tiles via gload_lds dbuf (16 tiles).
//   B: m1w fp32, 1 gldx4/thread depth-2. part bf16.
// ---------------------------------------------------------------------------
__global__ __launch_bounds__(512, 4) void k3_mlp1(
    const unsigned short* __restrict__ aggT,
    const float* __restrict__ Wm,          // [1024][16384]
    unsigned short* __restrict__ part)     // [16][256][1024] bf16
{
  const int bid = blockIdx.x;
  const int chunk = ((bid & 7) << 6) | (bid >> 3);
  const int s = chunk >> 5;                 // 0..15
  const int n0 = (chunk & 31) << 5;         // 0..992

  const int t = threadIdx.x, lane = t & 63, wave = t >> 6;
  const int wm = wave & 3, wn = wave >> 2;  // wn 0..1

  __shared__ __align__(16) unsigned char smem[73728]; // A:2x32K @0, B:2x4K @65536

  const char* Asrc = (const char*)aggT + (size_t)s * 16 * 32768 + wave * 1024 + lane * 16;
  const unsigned aoff = wave * 1024u;

  const int brow = t >> 4;                  // 0..31
  const int bcol = (t & 15) << 2;           // 0..60
  const float* Bsrc = Wm + (size_t)(n0 + brow) * 16384 + (size_t)s * 1024 + bcol;
  const unsigned bwoff = (unsigned)(((brow << 7) + (bcol << 1)) ^ ((brow & 7) << 4));

  f32x4 acc[4] = {};
  f32x4 pbA, pbB;

#define GLA(BUF, KT) do { \
    _Pragma("unroll") for (int _r = 0; _r < 4; ++_r) \
      gload16(Asrc + (KT) * 32768 + _r * 8192, \
              smem + (BUF) * 32768u + aoff + _r * 8192); } while (0)

#define BLOAD(PB, KT) (PB) = gldx4(Bsrc + (KT) * 64)

#define BSTORE(BUF, PB) \
    *(us4*)(smem + 65536u + (BUF) * 4096u + bwoff) = cvt4(PB)

#define COMP(BUF) do { \
    const unsigned char* Ab = smem + (BUF) * 32768u; \
    const unsigned char* Bb = smem + 65536u + (BUF) * 4096u; \
    const int fr = lane & 15, k16 = (lane >> 4) << 4; \
    _Pragma("unroll") for (int kk = 0; kk < 2; ++kk) { \
      short8 a[4], bfr; \
      _Pragma("unroll") for (int i = 0; i < 4; ++i) { \
        const int rw = (wm << 6) + (i << 4) + fr; \
        a[i] = *(const short8*)(Ab + (((rw << 7) + (kk << 6) + k16) ^ ((rw & 7) << 4))); \
      } \
      { const int rw = (wn << 4) + fr; \
        bfr = *(const short8*)(Bb + (((rw << 7) + (kk << 6) + k16) ^ ((rw & 7) << 4))); } \
      _Pragma("unroll") for (int i = 0; i < 4; ++i) \
        acc[i] = __builtin_amdgcn_mfma_f32_16x16x32_bf16(a[i], bfr, acc[i], 0, 0, 0); \
    } } while (0)

  // STEP invariant at entry: in-flight = B(KT+1) (1 load).
#define STEP(CUR, NXT, PBP, PBN, KT) do { \
    GLA(NXT, (KT) + 1);     /* 4 */ \
    BLOAD(PBN, (KT) + 2);   /* 1 */ \
    COMP(CUR); \
    WAITVM(1);   /* drain B(KT+1)+GLA; keep B(KT+2) */ \
    BSTORE(NXT, PBP); \
    sync_ds(); } while (0)

  GLA(0, 0);
  BLOAD(pbA, 0);
  BLOAD(pbB, 1);
  WAITVM(1);
  BSTORE(0, pbA);
  sync_ds();

#pragma unroll
  for (int kt = 0; kt < 14; kt += 2) {
    STEP(0, 1, pbB, pbA, kt);
    STEP(1, 0, pbA, pbB, kt + 1);
  }
  // tail: buf0 holds tile 14; pbB = B(15) in flight
  GLA(1, 15);
  COMP(0);            // tile 14
  WAITVM(0);
  BSTORE(1, pbB);
  sync_ds();
  COMP(1);            // tile 15

  const int col16 = lane & 15, row4 = (lane >> 4) << 2;
  unsigned short* outp = part + (size_t)s * BATCH * 1024;
#pragma unroll
  for (int i = 0; i < 4; ++i)
#pragma unroll
    for (int r = 0; r < 4; ++r)
      outp[(size_t)((wm << 6) + (i << 4) + row4 + r) * 1024
           + n0 + (wn << 4) + col16] = f2bf(acc[i][r]);
#undef STEP
#undef COMP
#undef GLA
#undef BLOAD
#undef BSTORE
}

// ---------------------------------------------------------------------------
// K4: fused head (bf16 partials). One block per batch row, 512 threads,
//     each thread owns 2 n's via one dword read per split.
// ---------------------------------------------------------------------------
__global__ __launch_bounds__(512) void k4_head(
    const unsigned short* __restrict__ part,   // [16][256][1024] bf16
    const float* __restrict__ b1,
    const float* __restrict__ w2,
    const float* __restrict__ b2,
    float* __restrict__ out)
{
  const int b = blockIdx.x;
  const int t = threadIdx.x;          // 0..511
  const int n0 = t << 1;
  float s0 = b1[n0], s1 = b1[n0 + 1];
#pragma unroll
  for (int sp = 0; sp < SPLIT; ++sp) {
    const unsigned u = *(const unsigned*)(part + ((size_t)sp * BATCH + b) * 1024 + n0);
    union { unsigned u; float f; } lo, hi;
    lo.u = u << 16;
    hi.u = u & 0xffff0000u;
    s0 += lo.f;
    s1 += hi.f;
  }
  float accum = fmaxf(s0, 0.0f) * w2[n0] + fmaxf(s1, 0.0f) * w2[n0 + 1];
  __shared__ float red[8];
#pragma unroll
  for (int off = 32; off > 0; off >>= 1)
    accum += __shfl_down(accum, off);
  if ((t & 63) == 0) red[t >> 6] = accum;
  __syncthreads();
  if (t == 0) {
    float r = b2[0];
#pragma unroll
    for (int w = 0; w < 8; ++w) r += red[w];
    out[b] = r;
  }
}

// ---------------------------------------------------------------------------
extern "C" void kernel_launch(void* const* d_in, const int* in_sizes, int n_in,
                              void* d_out, int out_size, void* d_ws, size_t ws_size,
                              hipStream_t stream) {
  const float* inputs = (const float*)d_in[0];
  const float* W_ih   = (const float*)d_in[1];
  // d_in[2] = W_hh: unused (h0 == 0)
  const float* b_ih   = (const float*)d_in[3];
  const float* b_hh   = (const float*)d_in[4];
  const float* imp    = (const float*)d_in[5];
  const float* m1w    = (const float*)d_in[6];
  const float* m1b    = (const float*)d_in[7];
  const float* m2w    = (const float*)d_in[8];
  const float* m2b    = (const float*)d_in[9];
  float* out = (float*)d_out;

  char* ws = (char*)d_ws;
  unsigned short* aggT = (unsigned short*)ws;                // 8 MB tiled bf16
  unsigned short* part = (unsigned short*)(ws + (8u << 20)); // 8 MB bf16

  k1_gates<<<dim3(512), 512, 0, stream>>>(inputs, W_ih, b_ih, b_hh, imp, aggT);
  k3_mlp1 <<<dim3(512), 512, 0, stream>>>(aggT, m1w, part);
  k4_head <<<dim3(256), 512, 0, stream>>>(part, m1b, m2w, m2b, out);
}